// Round 9
// baseline (675.277 us; speedup 1.0000x reference)
//
#include <hip/hip_runtime.h>
#include <math.h>

// MACE-like block. CSR-sorted edges + f16 MFMA R-GEMM fused with aggregation.
// R9: node kernels reverted to the measured-fast R5 structure ([m][c] LDS,
//     b32 broadcast reads) + 2 same-species nodes per wave (weight reuse,
//     L2 weight traffic halved). Wide-LDS-broadcast experiments (R6/R7)
//     measured slower and are abandoned.
// N=10000 nodes, E=160000 edges, C=64, 16 sph, S=10 species.

typedef _Float16 half8 __attribute__((ext_vector_type(8)));
typedef float f32x4 __attribute__((ext_vector_type(4)));

__device__ __forceinline__ float silu_f(float x) { return x / (1.0f + expf(-x)); }

__device__ __forceinline__ float reduce64(float v) {
#pragma unroll
  for (int off = 32; off > 0; off >>= 1) v += __shfl_xor(v, off, 64);
  return v;
}

__device__ __forceinline__ void compute_Y(float x, float y, float z, float* Y) {
  float x2 = x * x, y2 = y * y, z2 = z * z;
  Y[0] = 1.0f;
  Y[1] = 1.7320508f * x;
  Y[2] = 1.7320508f * y;
  Y[3] = 1.7320508f * z;
  Y[4] = 3.8729833f * x * y;
  Y[5] = 3.8729833f * y * z;
  Y[6] = 1.118034f * (3.0f * z2 - 1.0f);
  Y[7] = 3.8729833f * x * z;
  Y[8] = 1.9364917f * (x2 - y2);
  Y[9] = 2.09165f * y * (3.0f * x2 - y2);
  Y[10] = 10.246951f * x * y * z;
  Y[11] = 1.6201852f * y * (5.0f * z2 - 1.0f);
  Y[12] = 1.3228757f * z * (5.0f * z2 - 3.0f);
  Y[13] = 1.6201852f * x * (5.0f * z2 - 1.0f);
  Y[14] = 5.1234753f * z * (x2 - y2);
  Y[15] = 2.09165f * x * (x2 - 3.0f * y2);
}

__device__ __forceinline__ void compute_rb(float r, float inv_r, float* rb) {
  float t = fminf(r * 0.2f, 1.0f);
  float t2 = t * t;
  float t5 = t2 * t2 * t;
  float env = 1.0f + t5 * (-21.0f + t * (35.0f - 15.0f * t));
  float th = 0.62831853f * r;  // pi*r/5
  float s1 = sinf(th), c1 = cosf(th);
  float c2 = 2.0f * c1;
  float sprev = 0.0f, scur = s1;
  float coef = 0.63245553f * inv_r * env;
#pragma unroll
  for (int k = 0; k < 8; k++) {
    rb[k] = coef * scur;
    float snxt = c2 * scur - sprev;
    sprev = scur; scur = snxt;
  }
}

// ---------------------------------------------------------------- CSR build (edges)
__global__ __launch_bounds__(256) void k_hist(const int* __restrict__ receivers,
                                              int* __restrict__ cnt, int E) {
  int e = blockIdx.x * 256 + threadIdx.x;
  if (e < E) atomicAdd(&cnt[receivers[e]], 1);
}

__global__ __launch_bounds__(256) void k_scan(const int* __restrict__ deg,
                                              int* __restrict__ row_start,
                                              int* __restrict__ cursor, int N) {
  __shared__ int part[256];
  int t = threadIdx.x;
  int K = (N + 255) / 256;
  int lo = t * K, hi = min(lo + K, N);
  int s = 0;
  for (int i = lo; i < hi; i++) s += deg[i];
  part[t] = s;
  __syncthreads();
  for (int d = 1; d < 256; d <<= 1) {
    int v = (t >= d) ? part[t - d] : 0;
    __syncthreads();
    part[t] += v;
    __syncthreads();
  }
  int run = (t == 0) ? 0 : part[t - 1];
  for (int i = lo; i < hi; i++) {
    int di = deg[i];            // deg aliases cursor; read before overwrite
    row_start[i] = run;
    cursor[i] = run;
    run += di;
  }
  if (t == 255) row_start[N] = part[255];
}

__global__ __launch_bounds__(256) void k_scatter(const int* __restrict__ receivers,
                                                 const int* __restrict__ senders,
                                                 int* __restrict__ cursor,
                                                 int* __restrict__ perm,
                                                 int* __restrict__ rsort,
                                                 int* __restrict__ ssort, int E) {
  int e = blockIdx.x * 256 + threadIdx.x;
  if (e < E) {
    int r = receivers[e];
    int pos = atomicAdd(&cursor[r], 1);
    perm[pos] = e;
    rsort[pos] = r;
    ssort[pos] = senders[e];
  }
}

// ---------------------------------------------------------------- species sort (nodes)
__global__ __launch_bounds__(256) void k_nhist(const int* __restrict__ species,
                                               int* __restrict__ scnt, int N) {
  int n = blockIdx.x * 256 + threadIdx.x;
  if (n < N) atomicAdd(&scnt[species[n]], 1);
}

__global__ void k_nscan(int* __restrict__ scnt) {
  int run = 0;
#pragma unroll
  for (int s = 0; s < 10; s++) {
    int c = scnt[s];
    scnt[s] = run;
    run += ((c + 1) / 2) * 2;   // pair-align species groups
  }
}

__global__ __launch_bounds__(256) void k_nscatter(const int* __restrict__ species,
                                                  int* __restrict__ scnt,
                                                  int* __restrict__ nsort, int N) {
  int n = blockIdx.x * 256 + threadIdx.x;
  if (n < N) {
    int pos = atomicAdd(&scnt[species[n]], 1);
    nsort[pos] = n;
  }
}

// ---------------------------------------------------------------- pack rw2 -> f16 B^T
__global__ __launch_bounds__(256) void k_pack(const float* __restrict__ rw2,
                                              _Float16* __restrict__ b1t,
                                              _Float16* __restrict__ b2t) {
  int idx = blockIdx.x * 256 + threadIdx.x;
  if (idx < 16384) {
    int n = idx >> 6, k = idx & 63;
    int c = n >> 2, j = n & 3;
    b1t[idx] = (_Float16)rw2[k * 768 + c * 12 + j];
  } else if (idx < 40960) {
    int i2 = idx - 16384;
    int n = i2 >> 6, k = i2 & 63;
    int c = n / 6, j = n - c * 6;
    int col = (j < 4) ? j : ((j == 4) ? 5 : 9);
    b2t[i2] = (_Float16)rw2[49152 + k * 768 + c * 12 + col];
  }
}

// ---------------------------------------------------------------- up0
__global__ __launch_bounds__(256) void k_up0(const float* __restrict__ embed,
                                             const float* __restrict__ lu0,
                                             const int* __restrict__ species,
                                             float* __restrict__ up0, int N) {
  int wave = threadIdx.x >> 6, lane = threadIdx.x & 63;
  int n = (blockIdx.x << 2) + wave;
  if (n >= N) return;
  int sp = species[n];
  const float* er = embed + sp * 64;
  float acc = 0.0f;
#pragma unroll 8
  for (int c = 0; c < 64; c++) acc += er[c] * lu0[c * 64 + lane];
  up0[(size_t)n * 64 + lane] = acc;
}

// ---------------------------------------------------------------- geometry (sorted order)
__global__ __launch_bounds__(256) void k_geom(const float* __restrict__ ev,
                                              const float* __restrict__ rw1,
                                              const int* __restrict__ perm,
                                              _Float16* __restrict__ hid0,
                                              _Float16* __restrict__ hid1,
                                              float* __restrict__ Ysort,
                                              int* __restrict__ rsort,
                                              int* __restrict__ ssort,
                                              int E, int EPAD) {
  int wave = threadIdx.x >> 6, lane = threadIdx.x & 63;
  int j = blockIdx.x * 4 + wave;
  if (j >= EPAD) return;
  if (j >= E) {
    hid0[(size_t)j * 64 + lane] = (_Float16)0.0f;
    hid1[(size_t)j * 64 + lane] = (_Float16)0.0f;
    if (lane == 0) { rsort[j] = -1; ssort[j] = 0; }
    if (lane < 16) Ysort[(size_t)j * 16 + lane] = 0.0f;
    return;
  }
  int e = perm[j];
  float vx = ev[e * 3 + 0], vy = ev[e * 3 + 1], vz = ev[e * 3 + 2];
  float r = sqrtf(vx * vx + vy * vy + vz * vz);
  float inv_r = 1.0f / (r + 1e-8f);
  float Y[16]; compute_Y(vx * inv_r, vy * inv_r, vz * inv_r, Y);
  float rb[8]; compute_rb(r, inv_r, rb);

  float h0 = 0.0f, h1 = 0.0f;
#pragma unroll
  for (int k = 0; k < 8; k++) {
    h0 += rb[k] * rw1[k * 64 + lane];
    h1 += rb[k] * rw1[512 + k * 64 + lane];
  }
  hid0[(size_t)j * 64 + lane] = (_Float16)silu_f(h0);
  hid1[(size_t)j * 64 + lane] = (_Float16)silu_f(h1);

  float yv = Y[0];
#pragma unroll
  for (int m = 1; m < 16; m++) yv = (lane == m) ? Y[m] : yv;
  if (lane < 16) Ysort[(size_t)j * 16 + lane] = yv;
}

// ---------------------------------------------------------------- fused MFMA + agg, pass 1
__global__ __launch_bounds__(256) void k_fagg1(const _Float16* __restrict__ hid,
                                               const _Float16* __restrict__ bt,
                                               const float* __restrict__ Ysort,
                                               const float* __restrict__ up0,
                                               const int* __restrict__ ssort,
                                               const int* __restrict__ rsort,
                                               float* __restrict__ agg, int E) {
  __shared__ _Float16 __attribute__((aligned(16))) lds[4][16 * 256];  // 32 KB
  int wave = threadIdx.x >> 6, lane = threadIdx.x & 63;
  int q = lane >> 4, mr = lane & 15;
  _Float16* L = lds[wave];
  int j0 = __builtin_amdgcn_readfirstlane((blockIdx.x * 4 + wave) * 16);

  int rs[16], ss[16];
#pragma unroll
  for (int t = 0; t < 16; t++) {
    rs[t] = rsort[j0 + t];
    ss[t] = ssort[j0 + t];
  }
  float hsv[16];
#pragma unroll
  for (int t = 0; t < 16; t++)
    hsv[t] = up0[((size_t)ss[t] << 6) + lane];

  const half8* Ap = (const half8*)(hid + (size_t)(j0 + mr) * 64 + q * 8);
  half8 a0 = Ap[0];
  half8 a1 = Ap[4];
  const _Float16* bp = bt + (size_t)mr * 64 + q * 8;
#pragma unroll
  for (int T = 0; T < 16; T++) {
    half8 b0 = *(const half8*)(bp + T * 1024);
    half8 b1 = *(const half8*)(bp + T * 1024 + 32);
    f32x4 acc = {0.f, 0.f, 0.f, 0.f};
    acc = __builtin_amdgcn_mfma_f32_16x16x32_f16(a0, b0, acc, 0, 0, 0);
    acc = __builtin_amdgcn_mfma_f32_16x16x32_f16(a1, b1, acc, 0, 0, 0);
#pragma unroll
    for (int r = 0; r < 4; r++)
      L[(q * 4 + r) * 256 + T * 16 + mr] = (_Float16)acc[r];
  }

  float accm[16];
#pragma unroll
  for (int m = 0; m < 16; m++) accm[m] = 0.0f;
  int cur_r = (j0 < E) ? rs[0] : -1;

#pragma unroll
  for (int t = 0; t < 16; t++) {
    int j = j0 + t;
    bool ok = (j < E);
    int rr = ok ? rs[t] : -2;
    if (rr != cur_r) {
      if (cur_r >= 0) {
        float* base = agg + ((size_t)cur_r << 10) + lane;
#pragma unroll
        for (int m = 0; m < 16; m++) atomicAdd(base + (m << 6), accm[m]);
      }
#pragma unroll
      for (int m = 0; m < 16; m++) accm[m] = 0.0f;
      cur_r = rr;
    }
    if (ok) {
      float hs0 = hsv[t];
      const _Float16* Rr = L + t * 256 + lane * 4;
      float p0 = (float)Rr[0] * hs0, p1 = (float)Rr[1] * hs0;
      float p2 = (float)Rr[2] * hs0, p3 = (float)Rr[3] * hs0;
      const float* Yj = Ysort + (size_t)j * 16;
      float4 Ya = *(const float4*)(Yj);
      float4 Yb = *(const float4*)(Yj + 4);
      float4 Yc = *(const float4*)(Yj + 8);
      float4 Yd = *(const float4*)(Yj + 12);
      accm[0] += p0;
      accm[1] += p1 * Ya.y;  accm[2] += p1 * Ya.z;  accm[3] += p1 * Ya.w;
      accm[4] += p2 * Yb.x;  accm[5] += p2 * Yb.y;  accm[6] += p2 * Yb.z;
      accm[7] += p2 * Yb.w;  accm[8] += p2 * Yc.x;
      accm[9]  += p3 * Yc.y; accm[10] += p3 * Yc.z; accm[11] += p3 * Yc.w;
      accm[12] += p3 * Yd.x; accm[13] += p3 * Yd.y; accm[14] += p3 * Yd.z;
      accm[15] += p3 * Yd.w;
    }
  }
  if (cur_r >= 0) {
    float* base = agg + ((size_t)cur_r << 10) + lane;
#pragma unroll
    for (int m = 0; m < 16; m++) atomicAdd(base + (m << 6), accm[m]);
  }
}

// ---------------------------------------------------------------- fused MFMA + agg, pass 2
__global__ __launch_bounds__(256) void k_fagg2(const _Float16* __restrict__ hid,
                                               const _Float16* __restrict__ bt,
                                               const float* __restrict__ Ysort,
                                               const float* __restrict__ up1,
                                               const int* __restrict__ ssort,
                                               const int* __restrict__ rsort,
                                               float* __restrict__ agg, int E) {
  __shared__ _Float16 __attribute__((aligned(16))) lds[4][16 * 384];  // 48 KB
  int wave = threadIdx.x >> 6, lane = threadIdx.x & 63;
  int q = lane >> 4, mr = lane & 15;
  _Float16* L = lds[wave];
  int j0 = __builtin_amdgcn_readfirstlane((blockIdx.x * 4 + wave) * 16);

  int rs[16], ss[16];
#pragma unroll
  for (int t = 0; t < 16; t++) {
    rs[t] = rsort[j0 + t];
    ss[t] = ssort[j0 + t];
  }
  float4 hA[8];
#pragma unroll
  for (int t = 0; t < 8; t++)
    hA[t] = *(const float4*)(up1 + ((size_t)ss[t] << 8) + lane * 4);

  const half8* Ap = (const half8*)(hid + (size_t)(j0 + mr) * 64 + q * 8);
  half8 a0 = Ap[0];
  half8 a1 = Ap[4];
  const _Float16* bp = bt + (size_t)mr * 64 + q * 8;
#pragma unroll
  for (int T = 0; T < 24; T++) {
    half8 b0 = *(const half8*)(bp + T * 1024);
    half8 b1 = *(const half8*)(bp + T * 1024 + 32);
    f32x4 acc = {0.f, 0.f, 0.f, 0.f};
    acc = __builtin_amdgcn_mfma_f32_16x16x32_f16(a0, b0, acc, 0, 0, 0);
    acc = __builtin_amdgcn_mfma_f32_16x16x32_f16(a1, b1, acc, 0, 0, 0);
#pragma unroll
    for (int r = 0; r < 4; r++)
      L[(q * 4 + r) * 384 + T * 16 + mr] = (_Float16)acc[r];
  }

  float4 hB[8];
#pragma unroll
  for (int t = 0; t < 8; t++)
    hB[t] = *(const float4*)(up1 + ((size_t)ss[8 + t] << 8) + lane * 4);

  float accm[16];
#pragma unroll
  for (int m = 0; m < 16; m++) accm[m] = 0.0f;
  int cur_r = (j0 < E) ? rs[0] : -1;

#pragma unroll
  for (int t = 0; t < 16; t++) {
    int j = j0 + t;
    bool ok = (j < E);
    int rr = ok ? rs[t] : -2;
    if (rr != cur_r) {
      if (cur_r >= 0) {
        float* base = agg + ((size_t)cur_r << 10) + lane;
#pragma unroll
        for (int m = 0; m < 16; m++) atomicAdd(base + (m << 6), accm[m]);
      }
#pragma unroll
      for (int m = 0; m < 16; m++) accm[m] = 0.0f;
      cur_r = rr;
    }
    if (ok) {
      float4 hs = (t < 8) ? hA[t & 7] : hB[t & 7];
      float hs0 = hs.x, hs1 = hs.y, hs2 = hs.z, hs3 = hs.w;
      const _Float16* Rr = L + t * 384 + lane * 6;
      float R0 = (float)Rr[0], R1v = (float)Rr[1];
      float R2v = (float)Rr[2], R3v = (float)Rr[3];
      float c5 = (float)Rr[4], c9 = (float)Rr[5];
      float q0 = R0 * hs0, q1 = R1v * hs0, q2 = R2v * hs0, q3 = R3v * hs0;
      const float* Yj = Ysort + (size_t)j * 16;
      float4 Ya = *(const float4*)(Yj);
      float4 Yb = *(const float4*)(Yj + 4);
      float4 Yc = *(const float4*)(Yj + 8);
      float4 Yd = *(const float4*)(Yj + 12);
      accm[0] += q0 + c9 * (hs1 * Ya.y + hs2 * Ya.z + hs3 * Ya.w);
      accm[1] += q1 * Ya.y + c5 * hs1;
      accm[2] += q1 * Ya.z + c5 * hs2;
      accm[3] += q1 * Ya.w + c5 * hs3;
      accm[4] += q2 * Yb.x;  accm[5] += q2 * Yb.y;  accm[6] += q2 * Yb.z;
      accm[7] += q2 * Yb.w;  accm[8] += q2 * Yc.x;
      accm[9]  += q3 * Yc.y; accm[10] += q3 * Yc.z; accm[11] += q3 * Yc.w;
      accm[12] += q3 * Yd.x; accm[13] += q3 * Yd.y; accm[14] += q3 * Yd.z;
      accm[15] += q3 * Yd.w;
    }
  }
  if (cur_r >= 0) {
    float* base = agg + ((size_t)cur_r << 10) + lane;
#pragma unroll
    for (int m = 0; m < 16; m++) atomicAdd(base + (m << 6), accm[m]);
  }
}

// ---------------------------------------------------------------- node kernel 1
// R5 structure (1 wave/block, [m][c] LDS, b32 broadcast reads, l-grouped
// weight reuse) + 2 same-species nodes per wave: each weight load feeds both.
__global__ __launch_bounds__(64) void k_node1(float* __restrict__ agg0,
                                              const float* __restrict__ ld0,
                                              const float* __restrict__ sel_w,
                                              const float* __restrict__ pw0,
                                              const float* __restrict__ res_w,
                                              const float* __restrict__ lu1,
                                              const float* __restrict__ read0,
                                              const int* __restrict__ species,
                                              const int* __restrict__ nsort,
                                              float* __restrict__ out,
                                              float* __restrict__ res,
                                              float* __restrict__ up1) {
  int d = threadIdx.x;
  int i0 = blockIdx.x * 2;
  int n0 = nsort[i0], n1 = nsort[i0 + 1];
  if (n0 < 0) return;            // padded tail
  bool ok1 = (n1 >= 0);
  int nv1 = ok1 ? n1 : n0;
  int sp = species[n0];
  __shared__ float sA0[1024], sB0[1024], sA1[1024], sB1[1024];  // 16 KB

  // load agg (scaled); zero agg in place for fagg2
  {
    float* ag = agg0 + ((size_t)n0 << 10);
#pragma unroll
    for (int m = 0; m < 16; m++) {
      sA0[m * 64 + d] = ag[(m << 6) + d] * 0.0625f;
      ag[(m << 6) + d] = 0.0f;
    }
    float* ag1 = agg0 + ((size_t)nv1 << 10);
#pragma unroll
    for (int m = 0; m < 16; m++) {
      sA1[m * 64 + d] = ag1[(m << 6) + d] * 0.0625f;
      if (ok1) ag1[(m << 6) + d] = 0.0f;
    }
  }
  __syncthreads();

  // stage A: fint = agg @ ld0[l]
  float fr0[16], fr1[16];
#pragma unroll
  for (int m = 0; m < 16; m++) { fr0[m] = 0.0f; fr1[m] = 0.0f; }
#pragma unroll
  for (int l = 0; l < 4; l++) {
    int m0 = l * l, m1 = (l + 1) * (l + 1);
    const float* W = ld0 + l * 4096 + d;
#pragma unroll 8
    for (int c = 0; c < 64; c++) {
      float w = W[c * 64];
      for (int m = m0; m < m1; m++) {
        fr0[m] += sA0[m * 64 + c] * w;
        fr1[m] += sA1[m * 64 + c] * w;
      }
    }
  }
#pragma unroll
  for (int m = 0; m < 16; m++) { sB0[m * 64 + d] = fr0[m]; sB1[m * 64 + d] = fr1[m]; }
  __syncthreads();

  // stage B: f = fint @ sel_w[sp][l]
  float f20[16], f21[16];
#pragma unroll
  for (int m = 0; m < 16; m++) { f20[m] = 0.0f; f21[m] = 0.0f; }
#pragma unroll
  for (int l = 0; l < 4; l++) {
    int m0 = l * l, m1 = (l + 1) * (l + 1);
    const float* W = sel_w + ((size_t)(sp * 4 + l) << 12) + d;
#pragma unroll 8
    for (int c = 0; c < 64; c++) {
      float w = W[c * 64];
      for (int m = m0; m < m1; m++) {
        f20[m] += sB0[m * 64 + c] * w;
        f21[m] += sB1[m * 64 + c] * w;
      }
    }
  }
  {
    float s0 = f20[0], tt = 1.0f + s0 + s0 * s0;
#pragma unroll
    for (int m = 0; m < 4; m++) sA0[m * 64 + d] = f20[m] * tt;
    float s1 = f21[0], tu = 1.0f + s1 + s1 * s1;
#pragma unroll
    for (int m = 0; m < 4; m++) sA1[m * 64 + d] = f21[m] * tu;
  }
  __syncthreads();

  // stage C: f1 = tf @ prod_w0[sp], m<4
  float f10[4] = {0.f, 0.f, 0.f, 0.f}, f11[4] = {0.f, 0.f, 0.f, 0.f};
  {
    const float* W = pw0 + ((size_t)sp << 12) + d;
#pragma unroll 8
    for (int c = 0; c < 64; c++) {
      float w = W[c * 64];
#pragma unroll
      for (int m = 0; m < 4; m++) {
        f10[m] += sA0[m * 64 + c] * w;
        f11[m] += sA1[m * 64 + c] * w;
      }
    }
  }
#pragma unroll
  for (int m = 0; m < 4; m++) { sB0[m * 64 + d] = f10[m]; sB1[m * 64 + d] = f11[m]; }
  __syncthreads();

  // out0 = f1[:,0] . read0
  float rd = read0[d];
  float v0 = reduce64(f10[0] * rd);
  float v1 = reduce64(f11[0] * rd);
  if (d == 0) {
    out[2 * n0] = v0;
    if (ok1) out[2 * n1] = v1;
  }

  // res = f1[:,0] @ res_w[sp]; up1[n][d][0] via lu1[0]
  float u00, u10;
  {
    const float* Wr = res_w + ((size_t)sp << 12) + d;
    const float* Wu = lu1 + d;
    float a0 = 0.f, b0 = 0.f, a1 = 0.f, b1 = 0.f;
#pragma unroll 8
    for (int c = 0; c < 64; c++) {
      float wr = Wr[c * 64], wu = Wu[c * 64];
      float fv0 = sB0[c], fv1 = sB1[c];
      a0 += fv0 * wr;  b0 += fv0 * wu;
      a1 += fv1 * wr;  b1 += fv1 * wu;
    }
    res[((size_t)n0 << 6) + d] = a0;  u00 = b0;
    if (ok1) res[((size_t)n1 << 6) + d] = a1;
    u10 = b1;
  }
  // up1[n][d][m] via lu1[1], m=1..3 (shared weight row); layout [n][d][4]
  {
    const float* Wu = lu1 + 4096 + d;
    float a01 = 0.f, a02 = 0.f, a03 = 0.f;
    float a11 = 0.f, a12 = 0.f, a13 = 0.f;
#pragma unroll 8
    for (int c = 0; c < 64; c++) {
      float w = Wu[c * 64];
      a01 += sB0[64 + c] * w;  a02 += sB0[128 + c] * w;  a03 += sB0[192 + c] * w;
      a11 += sB1[64 + c] * w;  a12 += sB1[128 + c] * w;  a13 += sB1[192 + c] * w;
    }
    *(float4*)(up1 + ((size_t)n0 << 8) + d * 4) = make_float4(u00, a01, a02, a03);
    if (ok1)
      *(float4*)(up1 + ((size_t)n1 << 8) + d * 4) = make_float4(u10, a11, a12, a13);
  }
}

// ---------------------------------------------------------------- node kernel 2
__global__ __launch_bounds__(64) void k_node2(const float* __restrict__ agg1,
                                              const float* __restrict__ ld1,
                                              const float* __restrict__ pw1,
                                              const float* __restrict__ res,
                                              const float* __restrict__ mlp_w1,
                                              const float* __restrict__ mlp_w2,
                                              const int* __restrict__ species,
                                              const int* __restrict__ nsort,
                                              float* __restrict__ out) {
  int d = threadIdx.x;
  int i0 = blockIdx.x * 2;
  int n0 = nsort[i0], n1 = nsort[i0 + 1];
  if (n0 < 0) return;
  bool ok1 = (n1 >= 0);
  int nv1 = ok1 ? n1 : n0;
  int sp = species[n0];
  __shared__ float sA0[1024], sA1[1024];   // 8 KB
  __shared__ float sv0[128], sv1[128];     // q (0..63) and f2 (64..127)

  {
    const float* ag = agg1 + ((size_t)n0 << 10);
    const float* ag1 = agg1 + ((size_t)nv1 << 10);
#pragma unroll
    for (int m = 0; m < 16; m++) {
      sA0[m * 64 + d] = ag[(m << 6) + d] * 0.0625f;
      sA1[m * 64 + d] = ag1[(m << 6) + d] * 0.0625f;
    }
  }
  __syncthreads();

  // g = agg @ ld1[l]
  float g0[16], g1[16];
#pragma unroll
  for (int m = 0; m < 16; m++) { g0[m] = 0.0f; g1[m] = 0.0f; }
#pragma unroll
  for (int l = 0; l < 4; l++) {
    int m0 = l * l, m1 = (l + 1) * (l + 1);
    const float* W = ld1 + l * 4096 + d;
#pragma unroll 8
    for (int c = 0; c < 64; c++) {
      float w = W[c * 64];
      for (int m = m0; m < m1; m++) {
        g0[m] += sA0[m * 64 + c] * w;
        g1[m] += sA1[m * 64 + c] * w;
      }
    }
  }
  float inv0 = g0[0], inv1 = g1[0];
#pragma unroll
  for (int m = 1; m < 16; m++) { inv0 += g0[m] * g0[m]; inv1 += g1[m] * g1[m]; }
  __syncthreads();
  sv0[d] = inv0 + inv0 * inv0;
  sv1[d] = inv1 + inv1 * inv1;
  __syncthreads();

  // f2 = q @ prod_w1[sp] + res
  float a0 = res[((size_t)n0 << 6) + d];
  float a1 = res[((size_t)nv1 << 6) + d];
  {
    const float* W = pw1 + ((size_t)sp << 12) + d;
#pragma unroll 8
    for (int c = 0; c < 64; c++) {
      float w = W[c * 64];
      a0 += sv0[c] * w;
      a1 += sv1[c] * w;
    }
  }
  sv0[64 + d] = a0;
  sv1[64 + d] = a1;
  __syncthreads();

  float val0 = 0.0f, val1 = 0.0f;
  if (d < 32) {
    float h0 = 0.0f, h1 = 0.0f;
#pragma unroll 8
    for (int c = 0; c < 64; c++) {
      float w = mlp_w1[c * 32 + d];
      h0 += sv0[64 + c] * w;
      h1 += sv1[64 + c] * w;
    }
    float w2 = mlp_w2[d];
    val0 = silu_f(h0) * w2;
    val1 = silu_f(h1) * w2;
  }
  val0 = reduce64(val0);
  val1 = reduce64(val1);
  if (d == 0) {
    out[2 * n0 + 1] = val0;
    if (ok1) out[2 * n1 + 1] = val1;
  }
}

// ---------------------------------------------------------------- launch
extern "C" void kernel_launch(void* const* d_in, const int* in_sizes, int n_in,
                              void* d_out, int out_size, void* d_ws, size_t ws_size,
                              hipStream_t stream) {
  const float* ev      = (const float*)d_in[0];
  const float* embed   = (const float*)d_in[1];
  const float* rw1     = (const float*)d_in[2];
  const float* rw2     = (const float*)d_in[3];
  const float* lu0     = (const float*)d_in[4];
  const float* lu1     = (const float*)d_in[5];
  const float* ld      = (const float*)d_in[6];
  const float* sel_w   = (const float*)d_in[7];
  const float* pw0     = (const float*)d_in[8];
  const float* pw1     = (const float*)d_in[9];
  const float* res_w   = (const float*)d_in[10];
  const float* read0   = (const float*)d_in[11];
  const float* mlp_w1  = (const float*)d_in[12];
  const float* mlp_w2  = (const float*)d_in[13];
  const int* species   = (const int*)d_in[14];
  const int* senders   = (const int*)d_in[15];
  const int* receivers = (const int*)d_in[16];
  float* out = (float*)d_out;

  int N = in_sizes[14];
  int E = in_sizes[15];
  int EPAD = ((E + 63) / 64) * 64;
  int NP = ((N + 10 * 2 + 1) / 2) * 2;   // species groups pair-aligned; -1 fill

  float* ws = (float*)d_ws;
  size_t o = 0;
  float* agg  = ws + o;  o += (size_t)N * 1024;
  float* up0  = ws + o;  o += (size_t)N * 64;
  float* up1  = ws + o;  o += (size_t)N * 256;    // layout [n][d][4]
  float* resb = ws + o;  o += (size_t)N * 64;
  _Float16* b1t  = (_Float16*)(ws + o); o += 8192;
  _Float16* b2t  = (_Float16*)(ws + o); o += 12288;
  _Float16* hid0 = (_Float16*)(ws + o); o += (size_t)EPAD * 32;
  _Float16* hid1 = (_Float16*)(ws + o); o += (size_t)EPAD * 32;
  float* Ysort = ws + o; o += (size_t)EPAD * 16;
  int* row_start = (int*)(ws + o); o += (size_t)N + 1;
  int* cursor    = (int*)(ws + o); o += (size_t)N;
  int* scnt      = (int*)(ws + o); o += 16;
  int* perm      = (int*)(ws + o); o += (size_t)E;
  int* rsort     = (int*)(ws + o); o += (size_t)EPAD;
  int* ssort     = (int*)(ws + o); o += (size_t)EPAD;
  int* nsort     = (int*)(ws + o); o += (size_t)NP;

  hipMemsetAsync(agg, 0, (size_t)N * 1024 * sizeof(float), stream);
  hipMemsetAsync(cursor, 0, ((size_t)N + 16) * sizeof(int), stream);  // cursor + scnt
  hipMemsetAsync(nsort, 0xFF, (size_t)NP * sizeof(int), stream);      // -1 fill

  // CSR build (edges, shared by both interactions)
  k_hist<<<(E + 255) / 256, 256, 0, stream>>>(receivers, cursor, E);
  k_scan<<<1, 256, 0, stream>>>(cursor, row_start, cursor, N);
  k_scatter<<<(E + 255) / 256, 256, 0, stream>>>(receivers, senders, cursor,
                                                 perm, rsort, ssort, E);

  // species sort (nodes)
  k_nhist<<<(N + 255) / 256, 256, 0, stream>>>(species, scnt, N);
  k_nscan<<<1, 1, 0, stream>>>(scnt);
  k_nscatter<<<(N + 255) / 256, 256, 0, stream>>>(species, scnt, nsort, N);

  k_pack<<<160, 256, 0, stream>>>(rw2, b1t, b2t);
  k_up0<<<(N + 3) / 4, 256, 0, stream>>>(embed, lu0, species, up0, N);
  k_geom<<<EPAD / 4, 256, 0, stream>>>(ev, rw1, perm, hid0, hid1, Ysort,
                                       rsort, ssort, E, EPAD);

  int fblocks = EPAD / 64;
  k_fagg1<<<fblocks, 256, 0, stream>>>(hid0, b1t, Ysort, up0, ssort, rsort, agg, E);
  k_node1<<<NP / 2, 64, 0, stream>>>(agg, ld, sel_w, pw0, res_w, lu1, read0,
                                     species, nsort, out, resb, up1);
  k_fagg2<<<fblocks, 256, 0, stream>>>(hid1, b2t, Ysort, up1, ssort, rsort, agg, E);
  k_node2<<<NP / 2, 64, 0, stream>>>(agg, ld + 16384, pw1, resb, mlp_w1, mlp_w2,
                                     species, nsort, out);
}

// Round 12
// 417.327 us; speedup vs baseline: 1.6181x; 1.6181x over previous
//
#include <hip/hip_runtime.h>
#include <math.h>

// MACE-like block on gfx950. CSR-sorted edge aggregation + f16 MFMA radial
// GEMM fused with message/scatter; node transforms in the measured-best R5
// access pattern.
//
// R12: functionally identical to R10/R11 (never executed — two container
// infra failures); source hash intentionally perturbed to rule out a
// poisoned build cache. Content:
//   * dead-code pruning: reference consumes only f[:, :, :4] after sel_w and
//     interaction 1 has n_lin == 1, so interaction-1's aggregate needs only
//     m < 4 and radial columns {0,1}. fagg1 MFMA tile 256 -> 128 cols,
//     4 accumulators + 4 atomics per flush, agg-1 buffer N*256 floats.
//   * k_node1 stages A/B/C operate on 4 m's instead of 16 (~2.4x less work).
//   * node kernels keep the R5 [m][c]-LDS / b32-broadcast structure exactly
//     (R6/R7/R9 restructurings all measured slower).
// Sizes: N=10000 nodes, E=160000 edges, C=64, 16 sph, S=10 species.

#define WAVE_SZ 64

typedef _Float16 half8 __attribute__((ext_vector_type(8)));
typedef float f32x4 __attribute__((ext_vector_type(4)));

__device__ __forceinline__ float silu_f(float x) { return x / (1.0f + expf(-x)); }

__device__ __forceinline__ float reduce64(float v) {
#pragma unroll
  for (int off = 32; off > 0; off >>= 1) v += __shfl_xor(v, off, WAVE_SZ);
  return v;
}

__device__ __forceinline__ void compute_Y(float x, float y, float z, float* Y) {
  float x2 = x * x, y2 = y * y, z2 = z * z;
  Y[0] = 1.0f;
  Y[1] = 1.7320508f * x;
  Y[2] = 1.7320508f * y;
  Y[3] = 1.7320508f * z;
  Y[4] = 3.8729833f * x * y;
  Y[5] = 3.8729833f * y * z;
  Y[6] = 1.118034f * (3.0f * z2 - 1.0f);
  Y[7] = 3.8729833f * x * z;
  Y[8] = 1.9364917f * (x2 - y2);
  Y[9] = 2.09165f * y * (3.0f * x2 - y2);
  Y[10] = 10.246951f * x * y * z;
  Y[11] = 1.6201852f * y * (5.0f * z2 - 1.0f);
  Y[12] = 1.3228757f * z * (5.0f * z2 - 3.0f);
  Y[13] = 1.6201852f * x * (5.0f * z2 - 1.0f);
  Y[14] = 5.1234753f * z * (x2 - y2);
  Y[15] = 2.09165f * x * (x2 - 3.0f * y2);
}

__device__ __forceinline__ void compute_rb(float r, float inv_r, float* rb) {
  float t = fminf(r * 0.2f, 1.0f);
  float t2 = t * t;
  float t5 = t2 * t2 * t;
  float env = 1.0f + t5 * (-21.0f + t * (35.0f - 15.0f * t));
  float th = 0.62831853f * r;  // pi * r / 5
  float s1 = sinf(th), c1 = cosf(th);
  float c2 = 2.0f * c1;
  float sprev = 0.0f, scur = s1;
  float coef = 0.63245553f * inv_r * env;
#pragma unroll
  for (int k = 0; k < 8; k++) {
    rb[k] = coef * scur;
    float snxt = c2 * scur - sprev;
    sprev = scur;
    scur = snxt;
  }
}

// ------------------------------------------------------------- CSR build (edges)
__global__ __launch_bounds__(256) void k_hist(const int* __restrict__ receivers,
                                              int* __restrict__ cnt, int E) {
  int e = blockIdx.x * 256 + threadIdx.x;
  if (e < E) atomicAdd(&cnt[receivers[e]], 1);
}

__global__ __launch_bounds__(256) void k_scan(const int* __restrict__ deg,
                                              int* __restrict__ row_start,
                                              int* __restrict__ cursor, int N) {
  __shared__ int part[256];
  int t = threadIdx.x;
  int K = (N + 255) / 256;
  int lo = t * K, hi = min(lo + K, N);
  int s = 0;
  for (int i = lo; i < hi; i++) s += deg[i];
  part[t] = s;
  __syncthreads();
  for (int d = 1; d < 256; d <<= 1) {
    int v = (t >= d) ? part[t - d] : 0;
    __syncthreads();
    part[t] += v;
    __syncthreads();
  }
  int run = (t == 0) ? 0 : part[t - 1];
  for (int i = lo; i < hi; i++) {
    int di = deg[i];  // deg aliases cursor; must read before overwrite
    row_start[i] = run;
    cursor[i] = run;
    run += di;
  }
  if (t == 255) row_start[N] = part[255];
}

__global__ __launch_bounds__(256) void k_scatter(const int* __restrict__ receivers,
                                                 const int* __restrict__ senders,
                                                 int* __restrict__ cursor,
                                                 int* __restrict__ perm,
                                                 int* __restrict__ rsort,
                                                 int* __restrict__ ssort, int E) {
  int e = blockIdx.x * 256 + threadIdx.x;
  if (e < E) {
    int r = receivers[e];
    int pos = atomicAdd(&cursor[r], 1);
    perm[pos] = e;
    rsort[pos] = r;
    ssort[pos] = senders[e];
  }
}

// ------------------------------------------------------------- pack rw2 -> f16 B^T
// b1t[n][k] with n = c*2+j, j in {0,1}            (128 x 64 halves)
// b2t[n][k] with n = c*6+j, cols {0,1,2,3,5,9}    (384 x 64 halves)
__global__ __launch_bounds__(256) void k_pack(const float* __restrict__ rw2,
                                              _Float16* __restrict__ b1t,
                                              _Float16* __restrict__ b2t) {
  int idx = blockIdx.x * 256 + threadIdx.x;
  if (idx < 8192) {
    int n = idx >> 6, k = idx & 63;
    int c = n >> 1, j = n & 1;
    b1t[idx] = (_Float16)rw2[k * 768 + c * 12 + j];
  } else if (idx < 32768) {
    int i2 = idx - 8192;
    int n = i2 >> 6, k = i2 & 63;
    int c = n / 6, j = n - c * 6;
    int col = (j < 4) ? j : ((j == 4) ? 5 : 9);
    b2t[i2] = (_Float16)rw2[49152 + k * 768 + c * 12 + col];
  }
}

// ------------------------------------------------------------- up0
__global__ __launch_bounds__(256) void k_up0(const float* __restrict__ embed,
                                             const float* __restrict__ lu0,
                                             const int* __restrict__ species,
                                             float* __restrict__ up0, int N) {
  int wave = threadIdx.x >> 6, lane = threadIdx.x & 63;
  int n = (blockIdx.x << 2) + wave;
  if (n >= N) return;
  int sp = species[n];
  const float* er = embed + sp * 64;
  float acc = 0.0f;
#pragma unroll 8
  for (int c = 0; c < 64; c++) acc += er[c] * lu0[c * 64 + lane];
  up0[(size_t)n * 64 + lane] = acc;
}

// ------------------------------------------------------------- geometry (sorted)
__global__ __launch_bounds__(256) void k_geom(const float* __restrict__ ev,
                                              const float* __restrict__ rw1,
                                              const int* __restrict__ perm,
                                              _Float16* __restrict__ hid0,
                                              _Float16* __restrict__ hid1,
                                              float* __restrict__ Ysort,
                                              int* __restrict__ rsort,
                                              int* __restrict__ ssort,
                                              int E, int EPAD) {
  int wave = threadIdx.x >> 6, lane = threadIdx.x & 63;
  int j = blockIdx.x * 4 + wave;
  if (j >= EPAD) return;
  if (j >= E) {
    hid0[(size_t)j * 64 + lane] = (_Float16)0.0f;
    hid1[(size_t)j * 64 + lane] = (_Float16)0.0f;
    if (lane == 0) { rsort[j] = -1; ssort[j] = 0; }
    if (lane < 16) Ysort[(size_t)j * 16 + lane] = 0.0f;
    return;
  }
  int e = perm[j];
  float vx = ev[e * 3 + 0], vy = ev[e * 3 + 1], vz = ev[e * 3 + 2];
  float r = sqrtf(vx * vx + vy * vy + vz * vz);
  float inv_r = 1.0f / (r + 1e-8f);
  float Y[16];
  compute_Y(vx * inv_r, vy * inv_r, vz * inv_r, Y);
  float rb[8];
  compute_rb(r, inv_r, rb);

  float h0 = 0.0f, h1 = 0.0f;
#pragma unroll
  for (int k = 0; k < 8; k++) {
    h0 += rb[k] * rw1[k * 64 + lane];
    h1 += rb[k] * rw1[512 + k * 64 + lane];
  }
  hid0[(size_t)j * 64 + lane] = (_Float16)silu_f(h0);
  hid1[(size_t)j * 64 + lane] = (_Float16)silu_f(h1);

  // lane m (m < 16) stores Y[m]; static selects avoid scratch spill
  float yv = Y[0];
#pragma unroll
  for (int m = 1; m < 16; m++) yv = (lane == m) ? Y[m] : yv;
  if (lane < 16) Ysort[(size_t)j * 16 + lane] = yv;
}

// ------------------------------------------------------------- fagg pass 1 (pruned)
// Only m < 4 of the aggregate is live downstream -> R cols {0,1}, 128-col
// MFMA tile, 4 accumulators, 4 atomics per receiver flush.
__global__ __launch_bounds__(256) void k_fagg1(const _Float16* __restrict__ hid,
                                               const _Float16* __restrict__ bt,
                                               const float* __restrict__ Ysort,
                                               const float* __restrict__ up0,
                                               const int* __restrict__ ssort,
                                               const int* __restrict__ rsort,
                                               float* __restrict__ agg1c, int E) {
  __shared__ _Float16 __attribute__((aligned(16))) lds[4][16 * 128];  // 16 KB
  int wave = threadIdx.x >> 6, lane = threadIdx.x & 63;
  int q = lane >> 4, mr = lane & 15;
  _Float16* L = lds[wave];
  int j0 = __builtin_amdgcn_readfirstlane((blockIdx.x * 4 + wave) * 16);

  int rs[16], ss[16];
#pragma unroll
  for (int t = 0; t < 16; t++) {
    rs[t] = rsort[j0 + t];
    ss[t] = ssort[j0 + t];
  }
  float hsv[16];
#pragma unroll
  for (int t = 0; t < 16; t++) hsv[t] = up0[((size_t)ss[t] << 6) + lane];

  const half8* Ap = (const half8*)(hid + (size_t)(j0 + mr) * 64 + q * 8);
  half8 a0 = Ap[0];
  half8 a1 = Ap[4];
  const _Float16* bp = bt + (size_t)mr * 64 + q * 8;
#pragma unroll
  for (int T = 0; T < 8; T++) {
    half8 b0 = *(const half8*)(bp + T * 1024);
    half8 b1 = *(const half8*)(bp + T * 1024 + 32);
    f32x4 acc = {0.f, 0.f, 0.f, 0.f};
    acc = __builtin_amdgcn_mfma_f32_16x16x32_f16(a0, b0, acc, 0, 0, 0);
    acc = __builtin_amdgcn_mfma_f32_16x16x32_f16(a1, b1, acc, 0, 0, 0);
#pragma unroll
    for (int r = 0; r < 4; r++)
      L[(q * 4 + r) * 128 + T * 16 + mr] = (_Float16)acc[r];
  }

  float accm[4] = {0.f, 0.f, 0.f, 0.f};
  int cur_r = (j0 < E) ? rs[0] : -1;

#pragma unroll
  for (int t = 0; t < 16; t++) {
    int j = j0 + t;
    bool ok = (j < E);
    int rr = ok ? rs[t] : -2;
    if (rr != cur_r) {  // wave-uniform branch
      if (cur_r >= 0) {
        float* base = agg1c + ((size_t)cur_r << 8) + lane;
#pragma unroll
        for (int m = 0; m < 4; m++) atomicAdd(base + (m << 6), accm[m]);
      }
#pragma unroll
      for (int m = 0; m < 4; m++) accm[m] = 0.0f;
      cur_r = rr;
    }
    if (ok) {
      float hs0 = hsv[t];
      const _Float16* Rr = L + t * 128 + lane * 2;
      float p0 = (float)Rr[0] * hs0;
      float p1 = (float)Rr[1] * hs0;
      float4 Ya = *(const float4*)(Ysort + (size_t)j * 16);  // wave-uniform
      accm[0] += p0;
      accm[1] += p1 * Ya.y;
      accm[2] += p1 * Ya.z;
      accm[3] += p1 * Ya.w;
    }
  }
  if (cur_r >= 0) {
    float* base = agg1c + ((size_t)cur_r << 8) + lane;
#pragma unroll
    for (int m = 0; m < 4; m++) atomicAdd(base + (m << 6), accm[m]);
  }
}

// ------------------------------------------------------------- fagg pass 2
__global__ __launch_bounds__(256) void k_fagg2(const _Float16* __restrict__ hid,
                                               const _Float16* __restrict__ bt,
                                               const float* __restrict__ Ysort,
                                               const float* __restrict__ up1,
                                               const int* __restrict__ ssort,
                                               const int* __restrict__ rsort,
                                               float* __restrict__ agg, int E) {
  __shared__ _Float16 __attribute__((aligned(16))) lds[4][16 * 384];  // 48 KB
  int wave = threadIdx.x >> 6, lane = threadIdx.x & 63;
  int q = lane >> 4, mr = lane & 15;
  _Float16* L = lds[wave];
  int j0 = __builtin_amdgcn_readfirstlane((blockIdx.x * 4 + wave) * 16);

  int rs[16], ss[16];
#pragma unroll
  for (int t = 0; t < 16; t++) {
    rs[t] = rsort[j0 + t];
    ss[t] = ssort[j0 + t];
  }
  float4 hA[8];
#pragma unroll
  for (int t = 0; t < 8; t++)
    hA[t] = *(const float4*)(up1 + ((size_t)ss[t] << 8) + lane * 4);

  const half8* Ap = (const half8*)(hid + (size_t)(j0 + mr) * 64 + q * 8);
  half8 a0 = Ap[0];
  half8 a1 = Ap[4];
  const _Float16* bp = bt + (size_t)mr * 64 + q * 8;
#pragma unroll
  for (int T = 0; T < 24; T++) {
    half8 b0 = *(const half8*)(bp + T * 1024);
    half8 b1 = *(const half8*)(bp + T * 1024 + 32);
    f32x4 acc = {0.f, 0.f, 0.f, 0.f};
    acc = __builtin_amdgcn_mfma_f32_16x16x32_f16(a0, b0, acc, 0, 0, 0);
    acc = __builtin_amdgcn_mfma_f32_16x16x32_f16(a1, b1, acc, 0, 0, 0);
#pragma unroll
    for (int r = 0; r < 4; r++)
      L[(q * 4 + r) * 384 + T * 16 + mr] = (_Float16)acc[r];
  }

  float4 hB[8];
#pragma unroll
  for (int t = 0; t < 8; t++)
    hB[t] = *(const float4*)(up1 + ((size_t)ss[8 + t] << 8) + lane * 4);

  float accm[16];
#pragma unroll
  for (int m = 0; m < 16; m++) accm[m] = 0.0f;
  int cur_r = (j0 < E) ? rs[0] : -1;

#pragma unroll
  for (int t = 0; t < 16; t++) {
    int j = j0 + t;
    bool ok = (j < E);
    int rr = ok ? rs[t] : -2;
    if (rr != cur_r) {
      if (cur_r >= 0) {
        float* base = agg + ((size_t)cur_r << 10) + lane;
#pragma unroll
        for (int m = 0; m < 16; m++) atomicAdd(base + (m << 6), accm[m]);
      }
#pragma unroll
      for (int m = 0; m < 16; m++) accm[m] = 0.0f;
      cur_r = rr;
    }
    if (ok) {
      float4 hs = (t < 8) ? hA[t & 7] : hB[t & 7];
      float hs0 = hs.x, hs1 = hs.y, hs2 = hs.z, hs3 = hs.w;
      const _Float16* Rr = L + t * 384 + lane * 6;
      float R0 = (float)Rr[0], R1v = (float)Rr[1];
      float R2v = (float)Rr[2], R3v = (float)Rr[3];
      float c5 = (float)Rr[4], c9 = (float)Rr[5];
      float q0 = R0 * hs0, q1 = R1v * hs0, q2 = R2v * hs0, q3 = R3v * hs0;
      const float* Yj = Ysort + (size_t)j * 16;
      float4 Ya = *(const float4*)(Yj);
      float4 Yb = *(const float4*)(Yj + 4);
      float4 Yc = *(const float4*)(Yj + 8);
      float4 Yd = *(const float4*)(Yj + 12);
      accm[0] += q0 + c9 * (hs1 * Ya.y + hs2 * Ya.z + hs3 * Ya.w);
      accm[1] += q1 * Ya.y + c5 * hs1;
      accm[2] += q1 * Ya.z + c5 * hs2;
      accm[3] += q1 * Ya.w + c5 * hs3;
      accm[4] += q2 * Yb.x;
      accm[5] += q2 * Yb.y;
      accm[6] += q2 * Yb.z;
      accm[7] += q2 * Yb.w;
      accm[8] += q2 * Yc.x;
      accm[9] += q3 * Yc.y;
      accm[10] += q3 * Yc.z;
      accm[11] += q3 * Yc.w;
      accm[12] += q3 * Yd.x;
      accm[13] += q3 * Yd.y;
      accm[14] += q3 * Yd.z;
      accm[15] += q3 * Yd.w;
    }
  }
  if (cur_r >= 0) {
    float* base = agg + ((size_t)cur_r << 10) + lane;
#pragma unroll
    for (int m = 0; m < 16; m++) atomicAdd(base + (m << 6), accm[m]);
  }
}

// ------------------------------------------------------------- node kernel 1
// R5 structure, pruned to m < 4: stage A/B use l=0 (m=0) and l=1 (m=1..3).
__global__ __launch_bounds__(64) void k_node1(const float* __restrict__ agg1c,
                                              const float* __restrict__ ld0,
                                              const float* __restrict__ sel_w,
                                              const float* __restrict__ pw0,
                                              const float* __restrict__ res_w,
                                              const float* __restrict__ lu1,
                                              const float* __restrict__ read0,
                                              const int* __restrict__ species,
                                              float* __restrict__ out,
                                              float* __restrict__ res,
                                              float* __restrict__ up1, int N) {
  int n = blockIdx.x, d = threadIdx.x;
  int sp = species[n];
  __shared__ float sA[256], sB[256];

  const float* ag = agg1c + ((size_t)n << 8);
#pragma unroll
  for (int m = 0; m < 4; m++) sA[m * 64 + d] = ag[(m << 6) + d] * 0.0625f;
  __syncthreads();

  // stage A: fint = agg @ ld0[l]
  float fr[4] = {0.f, 0.f, 0.f, 0.f};
  {
    const float* W0 = ld0 + d;
    const float* W1 = ld0 + 4096 + d;
#pragma unroll 8
    for (int c = 0; c < 64; c++) {
      float w0 = W0[c * 64], w1 = W1[c * 64];
      fr[0] += sA[c] * w0;
      fr[1] += sA[64 + c] * w1;
      fr[2] += sA[128 + c] * w1;
      fr[3] += sA[192 + c] * w1;
    }
  }
#pragma unroll
  for (int m = 0; m < 4; m++) sB[m * 64 + d] = fr[m];
  __syncthreads();

  // stage B: f = fint @ sel_w[sp][l]
  float f2r[4] = {0.f, 0.f, 0.f, 0.f};
  {
    const float* W0 = sel_w + ((size_t)(sp * 4) << 12) + d;
    const float* W1 = sel_w + ((size_t)(sp * 4 + 1) << 12) + d;
#pragma unroll 8
    for (int c = 0; c < 64; c++) {
      float w0 = W0[c * 64], w1 = W1[c * 64];
      f2r[0] += sB[c] * w0;
      f2r[1] += sB[64 + c] * w1;
      f2r[2] += sB[128 + c] * w1;
      f2r[3] += sB[192 + c] * w1;
    }
  }
  float s0 = f2r[0];
  float tt = 1.0f + s0 + s0 * s0;
#pragma unroll
  for (int m = 0; m < 4; m++) sA[m * 64 + d] = f2r[m] * tt;
  __syncthreads();

  // stage C: f1 = tf @ prod_w0[sp]
  float f1r[4] = {0.f, 0.f, 0.f, 0.f};
  {
    const float* W = pw0 + ((size_t)sp << 12) + d;
#pragma unroll 8
    for (int c = 0; c < 64; c++) {
      float w = W[c * 64];
#pragma unroll
      for (int m = 0; m < 4; m++) f1r[m] += sA[m * 64 + c] * w;
    }
  }
#pragma unroll
  for (int m = 0; m < 4; m++) sB[m * 64 + d] = f1r[m];
  __syncthreads();

  // out0 = f1[:, 0] . read0
  float v = reduce64(f1r[0] * read0[d]);
  if (d == 0) out[2 * n] = v;

  // res = f1[:, 0] @ res_w[sp]; up1[n][d][0] via lu1[0]
  float u0;
  {
    const float* Wr = res_w + ((size_t)sp << 12) + d;
    const float* Wu = lu1 + d;
    float a = 0.0f, b = 0.0f;
#pragma unroll 8
    for (int c = 0; c < 64; c++) {
      float fv = sB[c];
      a += fv * Wr[c * 64];
      b += fv * Wu[c * 64];
    }
    res[((size_t)n << 6) + d] = a;
    u0 = b;
  }
  // up1[n][d][m] via lu1[1], m = 1..3; layout [n][d][4]
  {
    const float* Wu = lu1 + 4096 + d;
    float a1 = 0.f, a2 = 0.f, a3 = 0.f;
#pragma unroll 8
    for (int c = 0; c < 64; c++) {
      float w = Wu[c * 64];
      a1 += sB[64 + c] * w;
      a2 += sB[128 + c] * w;
      a3 += sB[192 + c] * w;
    }
    *(float4*)(up1 + ((size_t)n << 8) + d * 4) = make_float4(u0, a1, a2, a3);
  }
}

// ------------------------------------------------------------- node kernel 2
__global__ __launch_bounds__(64) void k_node2(const float* __restrict__ agg1,
                                              const float* __restrict__ ld1,
                                              const float* __restrict__ pw1,
                                              const float* __restrict__ res,
                                              const float* __restrict__ mlp_w1,
                                              const float* __restrict__ mlp_w2,
                                              const int* __restrict__ species,
                                              float* __restrict__ out, int N) {
  int n = blockIdx.x, d = threadIdx.x;
  int sp = species[n];
  __shared__ float sA[1024];

  const float* ag = agg1 + ((size_t)n << 10);
#pragma unroll
  for (int m = 0; m < 16; m++) sA[m * 64 + d] = ag[(m << 6) + d] * 0.0625f;
  __syncthreads();

  float g[16];
#pragma unroll
  for (int m = 0; m < 16; m++) g[m] = 0.0f;
#pragma unroll
  for (int l = 0; l < 4; l++) {
    int m0 = l * l, m1 = (l + 1) * (l + 1);
    const float* W = ld1 + l * 4096 + d;
#pragma unroll 8
    for (int c = 0; c < 64; c++) {
      float w = W[c * 64];
      for (int m = m0; m < m1; m++) g[m] += sA[m * 64 + c] * w;
    }
  }
  float inv = g[0];
#pragma unroll
  for (int m = 1; m < 16; m++) inv += g[m] * g[m];
  float qv = inv + inv * inv;
  __syncthreads();
  sA[d] = qv;
  __syncthreads();

  float a = res[((size_t)n << 6) + d];
  {
    const float* W = pw1 + ((size_t)sp << 12) + d;
#pragma unroll 8
    for (int c = 0; c < 64; c++) a += sA[c] * W[c * 64];
  }
  sA[64 + d] = a;
  __syncthreads();

  float val = 0.0f;
  if (d < 32) {
    float h = 0.0f;
#pragma unroll 8
    for (int c = 0; c < 64; c++) h += sA[64 + c] * mlp_w1[c * 32 + d];
    val = silu_f(h) * mlp_w2[d];
  }
  val = reduce64(val);
  if (d == 0) out[2 * n + 1] = val;
}

// ------------------------------------------------------------- launch
extern "C" void kernel_launch(void* const* d_in, const int* in_sizes, int n_in,
                              void* d_out, int out_size, void* d_ws, size_t ws_size,
                              hipStream_t stream) {
  const float* ev      = (const float*)d_in[0];
  const float* embed   = (const float*)d_in[1];
  const float* rw1     = (const float*)d_in[2];
  const float* rw2     = (const float*)d_in[3];
  const float* lu0     = (const float*)d_in[4];
  const float* lu1     = (const float*)d_in[5];
  const float* ld      = (const float*)d_in[6];
  const float* sel_w   = (const float*)d_in[7];
  const float* pw0     = (const float*)d_in[8];
  const float* pw1     = (const float*)d_in[9];
  const float* res_w   = (const float*)d_in[10];
  const float* read0   = (const float*)d_in[11];
  const float* mlp_w1  = (const float*)d_in[12];
  const float* mlp_w2  = (const float*)d_in[13];
  const int* species   = (const int*)d_in[14];
  const int* senders   = (const int*)d_in[15];
  const int* receivers = (const int*)d_in[16];
  float* out = (float*)d_out;

  int N = in_sizes[14];
  int E = in_sizes[15];
  int EPAD = ((E + 63) / 64) * 64;

  float* ws = (float*)d_ws;
  size_t o = 0;
  float* agg   = ws + o;  o += (size_t)N * 1024;  // interaction-2 target (16 m)
  float* agg1c = ws + o;  o += (size_t)N * 256;   // interaction-1 target (4 m)
  float* up0   = ws + o;  o += (size_t)N * 64;
  float* up1   = ws + o;  o += (size_t)N * 256;   // layout [n][d][4]
  float* resb  = ws + o;  o += (size_t)N * 64;
  _Float16* b1t  = (_Float16*)(ws + o); o += 4096;   // 128 x 64 halves
  _Float16* b2t  = (_Float16*)(ws + o); o += 12288;  // 384 x 64 halves
  _Float16* hid0 = (_Float16*)(ws + o); o += (size_t)EPAD * 32;
  _Float16* hid1 = (_Float16*)(ws + o); o += (size_t)EPAD * 32;
  float* Ysort = ws + o;  o += (size_t)EPAD * 16;
  int* row_start = (int*)(ws + o); o += (size_t)N + 1;
  int* cursor    = (int*)(ws + o); o += (size_t)N;
  int* perm      = (int*)(ws + o); o += (size_t)E;
  int* rsort     = (int*)(ws + o); o += (size_t)EPAD;
  int* ssort     = (int*)(ws + o); o += (size_t)EPAD;

  // zero both scatter targets (contiguous) and the CSR counters
  hipMemsetAsync(agg, 0, (size_t)N * 1280 * sizeof(float), stream);
  hipMemsetAsync(cursor, 0, (size_t)N * sizeof(int), stream);

  // CSR build (shared by both interactions)
  k_hist<<<(E + 255) / 256, 256, 0, stream>>>(receivers, cursor, E);
  k_scan<<<1, 256, 0, stream>>>(cursor, row_start, cursor, N);
  k_scatter<<<(E + 255) / 256, 256, 0, stream>>>(receivers, senders, cursor,
                                                 perm, rsort, ssort, E);

  k_pack<<<128, 256, 0, stream>>>(rw2, b1t, b2t);
  k_up0<<<(N + 3) / 4, 256, 0, stream>>>(embed, lu0, species, up0, N);
  k_geom<<<EPAD / 4, 256, 0, stream>>>(ev, rw1, perm, hid0, hid1, Ysort,
                                       rsort, ssort, E, EPAD);

  int fblocks = EPAD / 64;
  k_fagg1<<<fblocks, 256, 0, stream>>>(hid0, b1t, Ysort, up0, ssort, rsort,
                                       agg1c, E);
  k_node1<<<N, 64, 0, stream>>>(agg1c, ld, sel_w, pw0, res_w, lu1, read0,
                                species, out, resb, up1, N);
  k_fagg2<<<fblocks, 256, 0, stream>>>(hid1, b2t, Ysort, up1, ssort, rsort,
                                       agg, E);
  k_node2<<<N, 64, 0, stream>>>(agg, ld + 16384, pw1, resb, mlp_w1, mlp_w2,
                                species, out, N);
}